// Round 6
// baseline (445.498 us; speedup 1.0000x reference)
//
#include <hip/hip_runtime.h>
#include <hip/hip_bf16.h>

#define B_DIM 512
#define T_DIM 512
#define IND 64
#define WIDTH 128
#define GAMMA 0.01f
#define EPS 0.01f

// ---------------------------------------------------------------------------
// Kernel 1: projection  out[m][w] = b[w] + sum_i x[m][i] * V[i][w]
// (unchanged from R2/R3: near BW roofline)
// ---------------------------------------------------------------------------
#define PJ_ROWS 16
#define PJ_NT ((B_DIM * T_DIM) / PJ_ROWS)  // 16384

__global__ __launch_bounds__(256) void proj_kernel(
    const float* __restrict__ x, const float* __restrict__ V,
    const float* __restrict__ bias, float* __restrict__ out) {
  __shared__ __align__(16) float xs[PJ_ROWS * IND];  // 4 KB

  const int tid = threadIdx.x;
  const int c2 = (tid & 63) * 2;
  const int rh = tid >> 6;

  float2 Vreg[IND];
#pragma unroll
  for (int k = 0; k < IND; ++k)
    Vreg[k] = *(const float2*)(V + k * WIDTH + c2);
  const float2 bb = *(const float2*)(bias + c2);

  for (int tile = blockIdx.x; tile < PJ_NT; tile += gridDim.x) {
    const size_t m0 = (size_t)tile * PJ_ROWS;
    __syncthreads();
#pragma unroll
    for (int q = 0; q < 4; ++q)
      xs[tid + 256 * q] = x[m0 * IND + tid + 256 * q];
    __syncthreads();

    float2 acc0 = bb, acc1 = bb, acc2 = bb, acc3 = bb;
#pragma unroll
    for (int k4 = 0; k4 < IND / 4; ++k4) {
      float4 xv0 = ((const float4*)&xs[(rh + 0) * IND])[k4];
      float4 xv1 = ((const float4*)&xs[(rh + 4) * IND])[k4];
      float4 xv2 = ((const float4*)&xs[(rh + 8) * IND])[k4];
      float4 xv3 = ((const float4*)&xs[(rh + 12) * IND])[k4];
#pragma unroll
      for (int j = 0; j < 4; ++j) {
        float2 v = Vreg[4 * k4 + j];
        float e0 = (j == 0) ? xv0.x : (j == 1) ? xv0.y : (j == 2) ? xv0.z : xv0.w;
        float e1 = (j == 0) ? xv1.x : (j == 1) ? xv1.y : (j == 2) ? xv1.z : xv1.w;
        float e2 = (j == 0) ? xv2.x : (j == 1) ? xv2.y : (j == 2) ? xv2.z : xv2.w;
        float e3 = (j == 0) ? xv3.x : (j == 1) ? xv3.y : (j == 2) ? xv3.z : xv3.w;
        acc0.x += e0 * v.x; acc0.y += e0 * v.y;
        acc1.x += e1 * v.x; acc1.y += e1 * v.y;
        acc2.x += e2 * v.x; acc2.y += e2 * v.y;
        acc3.x += e3 * v.x; acc3.y += e3 * v.y;
      }
    }
    *(float2*)(out + (m0 + rh + 0) * WIDTH + c2) = acc0;
    *(float2*)(out + (m0 + rh + 4) * WIDTH + c2) = acc1;
    *(float2*)(out + (m0 + rh + 8) * WIDTH + c2) = acc2;
    *(float2*)(out + (m0 + rh + 12) * WIDTH + c2) = acc3;
  }
}

// ---------------------------------------------------------------------------
// Kernel 2: MFMA recurrence. 32 blocks x 256 threads (4 waves); block owns
// 16 batch rows, wave w owns output cols [32w, 32w+32) (2 MFMA col-tiles).
// Per step: S@A' via 24x mfma_f32_16x16x32_bf16 (3-product bf16 splitting,
// gamma folded into A'), fp32 tail (tanh), state hi/lo written back to LDS
// (row-pad 8 bf16 -> conflict-free b128 frag reads). One barrier per step.
// Layout note: A- and B-fragments use the SAME (lane>>4, elem)->k indexing,
// so any bijective hw k-permutation cancels; m = lane&15 (A), n = lane&15
// (B), C/D row=(lane>>4)*4+reg, col=lane&15 (verified m89/m91).
// ---------------------------------------------------------------------------
typedef __attribute__((ext_vector_type(8))) short bf16x8;
typedef __attribute__((ext_vector_type(4))) float f32x4;

#define RS 136  // LDS row stride in bf16 elems (128 + 8 pad)

__global__ __launch_bounds__(256) void rnn_kernel(
    const float* __restrict__ W, const float* __restrict__ init,
    float* __restrict__ out, float* __restrict__ finals) {
  __shared__ short S[2][2][16][RS];  // [buf][hi/lo][row][k]  17.4 KB
  const int tid = threadIdx.x;
  const int w = tid >> 6;    // wave 0..3
  const int lane = tid & 63;
  const int q = lane >> 4;   // 0..3
  const int m16 = lane & 15; // 0..15
  const int rb0 = blockIdx.x * 16;

  // --- B-frags: A' = W - W^T - gamma*I, this wave's 32 cols, hi/lo bf16 ---
  bf16x8 Bhi[2][4], Blo[2][4];
#pragma unroll
  for (int tau = 0; tau < 2; ++tau) {
    const int c = w * 32 + tau * 16 + m16;
#pragma unroll
    for (int kc = 0; kc < 4; ++kc) {
#pragma unroll
      for (int e = 0; e < 8; ++e) {
        const int k = kc * 32 + q * 8 + e;
        float a = W[(size_t)k * WIDTH + c] - W[(size_t)c * WIDTH + k];
        if (k == c) a -= GAMMA;
        unsigned hib = __float_as_uint(a) >> 16;  // truncation-split
        float lof = a - __uint_as_float(hib << 16);
        Bhi[tau][kc][e] = (short)hib;
        Blo[tau][kc][e] = (short)(__float_as_uint(lof) >> 16);
      }
    }
  }

  // --- state registers (C-layout: row = q*4+r, col = w*32+tau*16+m16) ---
  float sreg[2][4], ucur[2][4], unxt[2][4];
  float* optr[2][4];
#pragma unroll
  for (int tau = 0; tau < 2; ++tau)
#pragma unroll
    for (int r = 0; r < 4; ++r) {
      const int row = q * 4 + r;
      const int col = w * 32 + tau * 16 + m16;
      sreg[tau][r] = init[(size_t)(rb0 + row) * WIDTH + col];
      optr[tau][r] = out + (size_t)(rb0 + row) * T_DIM * WIDTH + col;
      ucur[tau][r] = optr[tau][r][0];
      unxt[tau][r] = optr[tau][r][WIDTH];
      // initial state into buffer 0 (hi/lo split)
      float ns = sreg[tau][r];
      unsigned hib = __float_as_uint(ns) >> 16;
      float lof = ns - __uint_as_float(hib << 16);
      S[0][0][row][col] = (short)hib;
      S[0][1][row][col] = (short)(__float_as_uint(lof) >> 16);
    }
  __syncthreads();

#pragma unroll 1
  for (int t = 0; t < T_DIM; ++t) {
    const int p = t & 1;
    // A-frags: lane reads rows m16, 8 consecutive k per (kc, q)
    bf16x8 Ahi[4], Alo[4];
#pragma unroll
    for (int kc = 0; kc < 4; ++kc) {
      Ahi[kc] = *(const bf16x8*)&S[p][0][m16][kc * 32 + q * 8];
      Alo[kc] = *(const bf16x8*)&S[p][1][m16][kc * 32 + q * 8];
    }
    f32x4 C0 = {0.f, 0.f, 0.f, 0.f}, C1 = {0.f, 0.f, 0.f, 0.f};
#pragma unroll
    for (int kc = 0; kc < 4; ++kc) {
      C0 = __builtin_amdgcn_mfma_f32_16x16x32_bf16(Ahi[kc], Bhi[0][kc], C0, 0, 0, 0);
      C1 = __builtin_amdgcn_mfma_f32_16x16x32_bf16(Ahi[kc], Bhi[1][kc], C1, 0, 0, 0);
      C0 = __builtin_amdgcn_mfma_f32_16x16x32_bf16(Alo[kc], Bhi[0][kc], C0, 0, 0, 0);
      C1 = __builtin_amdgcn_mfma_f32_16x16x32_bf16(Alo[kc], Bhi[1][kc], C1, 0, 0, 0);
      C0 = __builtin_amdgcn_mfma_f32_16x16x32_bf16(Ahi[kc], Blo[0][kc], C0, 0, 0, 0);
      C1 = __builtin_amdgcn_mfma_f32_16x16x32_bf16(Ahi[kc], Blo[1][kc], C1, 0, 0, 0);
    }
    // tail: f = dot + u (gamma in A'); tanh = 1 - 2/(e^{2f}+1); ns = s+EPS*th
#pragma unroll
    for (int tau = 0; tau < 2; ++tau) {
#pragma unroll
      for (int r = 0; r < 4; ++r) {
        const float dot = tau ? C1[r] : C0[r];
        const float f = dot + ucur[tau][r];
        ucur[tau][r] = unxt[tau][r];
        unxt[tau][r] = optr[tau][r][2 * WIDTH];  // prefetch u[t+2] (in-bounds)
        const float e2 = exp2f(f * 2.8853900817779268f);  // e^{2f}
        const float th = fmaf(-2.0f, __builtin_amdgcn_rcpf(e2 + 1.0f), 1.0f);
        const float ns = fmaf(EPS, th, sreg[tau][r]);
        sreg[tau][r] = ns;
        optr[tau][r][0] = ns;  // overwrite u slot with output state
        optr[tau][r] += WIDTH;
        const int row = q * 4 + r;
        const int col = w * 32 + tau * 16 + m16;
        unsigned hib = __float_as_uint(ns) >> 16;
        float lof = ns - __uint_as_float(hib << 16);
        S[p ^ 1][0][row][col] = (short)hib;
        S[p ^ 1][1][row][col] = (short)(__float_as_uint(lof) >> 16);
      }
    }
    __syncthreads();
  }

#pragma unroll
  for (int tau = 0; tau < 2; ++tau)
#pragma unroll
    for (int r = 0; r < 4; ++r)
      finals[(size_t)(rb0 + q * 4 + r) * WIDTH + (w * 32 + tau * 16 + m16)] =
          sreg[tau][r];
}

extern "C" void kernel_launch(void* const* d_in, const int* in_sizes, int n_in,
                              void* d_out, int out_size, void* d_ws,
                              size_t ws_size, hipStream_t stream) {
  const float* x = (const float*)d_in[0];
  const float* init = (const float*)d_in[1];
  const float* W = (const float*)d_in[2];
  const float* V = (const float*)d_in[3];
  const float* bias = (const float*)d_in[4];

  float* out = (float*)d_out;
  float* finals = out + (size_t)B_DIM * T_DIM * WIDTH;

  proj_kernel<<<2048, 256, 0, stream>>>(x, V, bias, out);
  rnn_kernel<<<B_DIM / 16, 256, 0, stream>>>(W, init, out, finals);
}

// Round 7
// 305.747 us; speedup vs baseline: 1.4571x; 1.4571x over previous
//
#include <hip/hip_runtime.h>
#include <hip/hip_bf16.h>

#define B_DIM 512
#define T_DIM 512
#define IND 64
#define WIDTH 128
#define GAMMA 0.01f
#define EPS 0.01f

// ---------------------------------------------------------------------------
// Kernel 1: projection  out[m][w] = b[w] + sum_i x[m][i] * V[i][w]
// (unchanged from R2/R3: near BW roofline)
// ---------------------------------------------------------------------------
#define PJ_ROWS 16
#define PJ_NT ((B_DIM * T_DIM) / PJ_ROWS)  // 16384

__global__ __launch_bounds__(256) void proj_kernel(
    const float* __restrict__ x, const float* __restrict__ V,
    const float* __restrict__ bias, float* __restrict__ out) {
  __shared__ __align__(16) float xs[PJ_ROWS * IND];  // 4 KB

  const int tid = threadIdx.x;
  const int c2 = (tid & 63) * 2;
  const int rh = tid >> 6;

  float2 Vreg[IND];
#pragma unroll
  for (int k = 0; k < IND; ++k)
    Vreg[k] = *(const float2*)(V + k * WIDTH + c2);
  const float2 bb = *(const float2*)(bias + c2);

  for (int tile = blockIdx.x; tile < PJ_NT; tile += gridDim.x) {
    const size_t m0 = (size_t)tile * PJ_ROWS;
    __syncthreads();
#pragma unroll
    for (int q = 0; q < 4; ++q)
      xs[tid + 256 * q] = x[m0 * IND + tid + 256 * q];
    __syncthreads();

    float2 acc0 = bb, acc1 = bb, acc2 = bb, acc3 = bb;
#pragma unroll
    for (int k4 = 0; k4 < IND / 4; ++k4) {
      float4 xv0 = ((const float4*)&xs[(rh + 0) * IND])[k4];
      float4 xv1 = ((const float4*)&xs[(rh + 4) * IND])[k4];
      float4 xv2 = ((const float4*)&xs[(rh + 8) * IND])[k4];
      float4 xv3 = ((const float4*)&xs[(rh + 12) * IND])[k4];
#pragma unroll
      for (int j = 0; j < 4; ++j) {
        float2 v = Vreg[4 * k4 + j];
        float e0 = (j == 0) ? xv0.x : (j == 1) ? xv0.y : (j == 2) ? xv0.z : xv0.w;
        float e1 = (j == 0) ? xv1.x : (j == 1) ? xv1.y : (j == 2) ? xv1.z : xv1.w;
        float e2 = (j == 0) ? xv2.x : (j == 1) ? xv2.y : (j == 2) ? xv2.z : xv2.w;
        float e3 = (j == 0) ? xv3.x : (j == 1) ? xv3.y : (j == 2) ? xv3.z : xv3.w;
        acc0.x += e0 * v.x; acc0.y += e0 * v.y;
        acc1.x += e1 * v.x; acc1.y += e1 * v.y;
        acc2.x += e2 * v.x; acc2.y += e2 * v.y;
        acc3.x += e3 * v.x; acc3.y += e3 * v.y;
      }
    }
    *(float2*)(out + (m0 + rh + 0) * WIDTH + c2) = acc0;
    *(float2*)(out + (m0 + rh + 4) * WIDTH + c2) = acc1;
    *(float2*)(out + (m0 + rh + 8) * WIDTH + c2) = acc2;
    *(float2*)(out + (m0 + rh + 12) * WIDTH + c2) = acc3;
  }
}

// ---------------------------------------------------------------------------
// Kernel 2: recurrence (R3 structure). 256 threads/block = (colpair cp,
// k-chunk kc). 2 cols/thread, split-k=4, DPP quad reduce, double-buffered
// state, depth-2 u prefetch. KEY CHANGE vs R3: the per-step barrier is a raw
// "s_waitcnt lgkmcnt(0); s_barrier" (LDS-only drain). __syncthreads() drains
// vmcnt(0) too, which put the global u-load + out-store round trip
// (~400-900 cy) into every step's serial chain. Global ops are per-thread
// private here: the u[t+2] load is consumed (vmcnt-waited) before the same
// thread stores to that address at step t+2, and out-stores are never read
// by other waves. So leaving them in flight across the barrier is safe.
// ---------------------------------------------------------------------------
#define LDS_BARRIER() asm volatile("s_waitcnt lgkmcnt(0)\n\ts_barrier" ::: "memory")

template <int CTRL>
__device__ __forceinline__ float dpp_mov(float x) {
  return __int_as_float(
      __builtin_amdgcn_update_dpp(0, __float_as_int(x), CTRL, 0xf, 0xf, true));
}

__global__ __launch_bounds__(256) void rnn_kernel(
    const float* __restrict__ W, const float* __restrict__ init,
    float* __restrict__ out, float* __restrict__ finals) {
  __shared__ __align__(16) float sL[2][WIDTH];
  const int b = blockIdx.x;
  const int tid = threadIdx.x;
  const int kc = tid & 3;   // k-chunk, lane bits 0-1
  const int cp = tid >> 2;  // 0..63 column pair
  const int c0 = 2 * cp;

  // Areg[col][4j+m] = A[kc*32 + ((j+2kc)&7)*4 + m][c0+col],  A = W - W^T
  // (bank-stagger rotation baked in; register indices all compile-time)
  float Areg[2][32];
  {
    const int k0 = kc * 32;
#pragma unroll
    for (int j = 0; j < 8; ++j) {
      const int ri = (j + 2 * kc) & 7;  // runtime, addresses only
      const int k = k0 + ri * 4;
#pragma unroll
      for (int col = 0; col < 2; ++col) {
        const int cc = c0 + col;
        float4 wr = *(const float4*)(W + (size_t)cc * WIDTH + k);
        Areg[col][4 * j + 0] = W[(size_t)(k + 0) * WIDTH + cc] - wr.x;
        Areg[col][4 * j + 1] = W[(size_t)(k + 1) * WIDTH + cc] - wr.y;
        Areg[col][4 * j + 2] = W[(size_t)(k + 2) * WIDTH + cc] - wr.z;
        Areg[col][4 * j + 3] = W[(size_t)(k + 3) * WIDTH + cc] - wr.w;
      }
    }
  }

  float2 s = *(const float2*)(init + (size_t)b * WIDTH + c0);
  if (kc == 0) *(float2*)&sL[0][c0] = s;
  __syncthreads();

  float* outc = out + (size_t)b * T_DIM * WIDTH + c0;
  float2 u0 = *(const float2*)(outc);
  float2 u1 = *(const float2*)(outc + WIDTH);

#pragma unroll 1
  for (int t = 0; t < T_DIM; ++t) {
    const int p = t & 1;
    const float2 u = u0;
    u0 = u1;
    if (t + 2 < T_DIM) u1 = *(const float2*)(outc + (size_t)(t + 2) * WIDTH);

    const float4* sp = (const float4*)&sL[p][0];
    float a00 = 0.f, a01 = 0.f, a10 = 0.f, a11 = 0.f;
#pragma unroll
    for (int j = 0; j < 8; ++j) {
      const int ri = (j + 2 * kc) & 7;  // bank-staggered across kc groups
      float4 sv = sp[kc * 8 + ri];
      a00 += sv.x * Areg[0][4 * j + 0];
      a01 += sv.y * Areg[0][4 * j + 1];
      a00 += sv.z * Areg[0][4 * j + 2];
      a01 += sv.w * Areg[0][4 * j + 3];
      a10 += sv.x * Areg[1][4 * j + 0];
      a11 += sv.y * Areg[1][4 * j + 1];
      a10 += sv.z * Areg[1][4 * j + 2];
      a11 += sv.w * Areg[1][4 * j + 3];
    }
    float d0 = a00 + a01;
    float d1 = a10 + a11;
    // 4-way split-k sum over lane bits 0-1 via DPP (pure VALU)
    d0 += dpp_mov<0xB1>(d0);
    d1 += dpp_mov<0xB1>(d1);
    d0 += dpp_mov<0x4E>(d0);
    d1 += dpp_mov<0x4E>(d1);

    const float f0 = d0 - GAMMA * s.x + u.x;
    const float f1 = d1 - GAMMA * s.y + u.y;
    // tanh(f) = 1 - 2/(exp(2f)+1); inf-safe both directions
    const float e0 = __expf(2.0f * f0);
    const float e1 = __expf(2.0f * f1);
    const float th0 = fmaf(-2.0f, __builtin_amdgcn_rcpf(e0 + 1.0f), 1.0f);
    const float th1 = fmaf(-2.0f, __builtin_amdgcn_rcpf(e1 + 1.0f), 1.0f);
    s.x = fmaf(EPS, th0, s.x);
    s.y = fmaf(EPS, th1, s.y);

    if (kc == 0) {
      *(float2*)(outc + (size_t)t * WIDTH) = s;  // overwrite u slot
      *(float2*)&sL[p ^ 1][c0] = s;
    }
    LDS_BARRIER();  // LDS-only drain: global load/store stay in flight
  }

  if (kc == 0) *(float2*)(finals + (size_t)b * WIDTH + c0) = s;
}

extern "C" void kernel_launch(void* const* d_in, const int* in_sizes, int n_in,
                              void* d_out, int out_size, void* d_ws,
                              size_t ws_size, hipStream_t stream) {
  const float* x = (const float*)d_in[0];
  const float* init = (const float*)d_in[1];
  const float* W = (const float*)d_in[2];
  const float* V = (const float*)d_in[3];
  const float* bias = (const float*)d_in[4];

  float* out = (float*)d_out;
  float* finals = out + (size_t)B_DIM * T_DIM * WIDTH;

  proj_kernel<<<2048, 256, 0, stream>>>(x, V, bias, out);
  rnn_kernel<<<B_DIM, 256, 0, stream>>>(W, init, out, finals);
}